// Round 5
// baseline (365.062 us; speedup 1.0000x reference)
//
#include <hip/hip_runtime.h>
#include <stdint.h>

#define NN 50000
#define EE 800000
#define DD 128
#define GG 16
#define CC 10
#define NB 196                    // scan blocks: 196*256 = 50176 >= NN

typedef unsigned short u16;
typedef __bf16 bf16x8 __attribute__((ext_vector_type(8)));
typedef float f32x4 __attribute__((ext_vector_type(4)));

__device__ inline u16 f2bf(float f) {
    unsigned u = __float_as_uint(f);
    u = u + 0x7fffu + ((u >> 16) & 1u);   // RNE
    return (u16)(u >> 16);
}
__device__ inline unsigned pack2(float a, float b) {
    return (unsigned)f2bf(a) | ((unsigned)f2bf(b) << 16);
}
__device__ inline float bf2f(unsigned bits16) { return __uint_as_float(bits16 << 16); }
__device__ inline void acc8(float* a, uint4 v) {
    a[0] += __uint_as_float(v.x << 16); a[1] += __uint_as_float(v.x & 0xffff0000u);
    a[2] += __uint_as_float(v.y << 16); a[3] += __uint_as_float(v.y & 0xffff0000u);
    a[4] += __uint_as_float(v.z << 16); a[5] += __uint_as_float(v.z & 0xffff0000u);
    a[6] += __uint_as_float(v.w << 16); a[7] += __uint_as_float(v.w & 0xffff0000u);
}

// ---------- fused prep: zero (deg|cur|pool), cvt h->bf16, transpose+cast weights ----------
#define PZ (2 * NN + GG * DD)          // 102048 ints to zero
#define PC (NN * DD / 4)               // 1600000 float4 groups
#define PW (4 * DD * DD)               // 65536 weight elements
#define PTOT (PZ + PC + PW)

__global__ void prep_kernel(const float* __restrict__ h,
                            const float* __restrict__ a, const float* __restrict__ b,
                            const float* __restrict__ c, const float* __restrict__ d,
                            int* __restrict__ zbase, u16* __restrict__ H0,
                            u16* __restrict__ wt) {
    int i = blockIdx.x * 256 + threadIdx.x;
    if (i < PZ) { zbase[i] = 0; return; }
    i -= PZ;
    if (i < PC) {
        int j = i * 4;
        float4 v = *(const float4*)(h + j);
        ushort4 o;
        o.x = f2bf(v.x); o.y = f2bf(v.y); o.z = f2bf(v.z); o.w = f2bf(v.w);
        *(ushort4*)(H0 + j) = o;
        return;
    }
    i -= PC;
    if (i < PW) {
        int m = i >> 14, r = i & 16383, k = r >> 7, j = r & 127;
        const float* W = (m == 0) ? a : (m == 1) ? b : (m == 2) ? c : d;
        wt[(m << 14) + (j << 7) + k] = f2bf(W[(k << 7) + j]);
    }
}

// ---------- CSR build ----------
__global__ void hist_kernel(const int* __restrict__ dst, int* __restrict__ deg) {
    int e = blockIdx.x * 256 + threadIdx.x;
    if (e < EE) atomicAdd(&deg[dst[e]], 1);
}

__global__ void scanA_kernel(const int* __restrict__ deg, int* __restrict__ offs,
                             int* __restrict__ bsum) {
    __shared__ int tmp[256];
    int t = threadIdx.x, idx = blockIdx.x * 256 + t;
    int v = (idx < NN) ? deg[idx] : 0;
    tmp[t] = v; __syncthreads();
    for (int off = 1; off < 256; off <<= 1) {
        int x = (t >= off) ? tmp[t - off] : 0;
        __syncthreads();
        tmp[t] += x;
        __syncthreads();
    }
    if (idx < NN) offs[idx] = tmp[t] - v;          // exclusive within block
    if (t == 255) bsum[blockIdx.x] = tmp[255];
}

// scans the NB block sums; also computes graph boundaries (fused)
__global__ void scanB_kernel(int* __restrict__ bsum, int* __restrict__ offs,
                             const int* __restrict__ gids, int* __restrict__ gstart) {
    __shared__ int tmp[256];
    int t = threadIdx.x;
    if (t <= GG) {                                  // graph boundary binary search
        int lo = 0, hi = NN;
        while (lo < hi) { int mid = (lo + hi) >> 1; if (gids[mid] < t) lo = mid + 1; else hi = mid; }
        gstart[t] = lo;
    }
    int v = (t < NB) ? bsum[t] : 0;
    tmp[t] = v; __syncthreads();
    for (int off = 1; off < 256; off <<= 1) {
        int x = (t >= off) ? tmp[t - off] : 0;
        __syncthreads();
        tmp[t] += x;
        __syncthreads();
    }
    if (t < NB) bsum[t] = tmp[t] - v;               // exclusive block offsets
    if (t == NB - 1) offs[NN] = tmp[t];             // grand total (= EE)
}

__global__ void scanC_kernel(int* __restrict__ offs, const int* __restrict__ bsum) {
    int idx = blockIdx.x * 256 + threadIdx.x;
    if (idx < NN) offs[idx] += bsum[blockIdx.x];
}

__global__ void scatter_kernel(const int* __restrict__ src, const int* __restrict__ dst,
                               const int* __restrict__ offs, int* __restrict__ cur,
                               int* __restrict__ ssrc) {
    int e = blockIdx.x * 256 + threadIdx.x;
    if (e >= EE) return;
    int d = dst[e];
    int pos = offs[d] + atomicAdd(&cur[d], 1);
    ssrc[pos] = src[e];
}

// ---------- aggregation: z = h + sum_{incoming} h_src ----------
// work item = (node, 128B half-row); 8 lanes per item, 8 items per wave.
// grid 3125 blocks -> 12.5k waves -> 8 waves/SIMD. Edge loop: software-pipelined
// unroll-8 with next-batch index prefetch -> ~10 VMEM instrs in flight per wave
// (vs 4 before), hiding the idx->addr->data 2-level chain.
__global__ __launch_bounds__(256) void agg_kernel(
    const u16* __restrict__ Hin, const int* __restrict__ offs,
    const int* __restrict__ ssrc, u16* __restrict__ Z) {
    int gid = blockIdx.x * 32 + (threadIdx.x >> 3);   // 0..99999
    int lid = threadIdx.x & 7;
    if (gid >= 2 * NN) return;
    int node = gid >> 1;
    int foff = (gid & 1) * 64 + lid * 8;              // 16B slice
    const u16* base = Hin + foff;

    float acc[8] = {0.f, 0.f, 0.f, 0.f, 0.f, 0.f, 0.f, 0.f};
    uint4 vs = *(const uint4*)(base + (size_t)node * DD);
    int e = offs[node], e1 = offs[node + 1];
    acc8(acc, vs);                                    // self term (eps=0)

    int i0 = 0, i1 = 0, i2 = 0, i3 = 0, i4 = 0, i5 = 0, i6 = 0, i7 = 0;
    bool have = (e + 8 <= e1);
    if (have) {
        i0 = ssrc[e];     i1 = ssrc[e + 1]; i2 = ssrc[e + 2]; i3 = ssrc[e + 3];
        i4 = ssrc[e + 4]; i5 = ssrc[e + 5]; i6 = ssrc[e + 6]; i7 = ssrc[e + 7];
    }
    while (have) {
        int en = e + 8;
        bool haven = (en + 8 <= e1);
        int n0 = i0, n1 = i1, n2 = i2, n3 = i3, n4 = i4, n5 = i5, n6 = i6, n7 = i7;
        if (haven) {                                   // prefetch next batch indices
            n0 = ssrc[en];     n1 = ssrc[en + 1]; n2 = ssrc[en + 2]; n3 = ssrc[en + 3];
            n4 = ssrc[en + 4]; n5 = ssrc[en + 5]; n6 = ssrc[en + 6]; n7 = ssrc[en + 7];
        }
        uint4 v0 = *(const uint4*)(base + (size_t)i0 * DD);
        uint4 v1 = *(const uint4*)(base + (size_t)i1 * DD);
        uint4 v2 = *(const uint4*)(base + (size_t)i2 * DD);
        uint4 v3 = *(const uint4*)(base + (size_t)i3 * DD);
        uint4 v4 = *(const uint4*)(base + (size_t)i4 * DD);
        uint4 v5 = *(const uint4*)(base + (size_t)i5 * DD);
        uint4 v6 = *(const uint4*)(base + (size_t)i6 * DD);
        uint4 v7 = *(const uint4*)(base + (size_t)i7 * DD);
        acc8(acc, v0); acc8(acc, v1); acc8(acc, v2); acc8(acc, v3);
        acc8(acc, v4); acc8(acc, v5); acc8(acc, v6); acc8(acc, v7);
        i0 = n0; i1 = n1; i2 = n2; i3 = n3; i4 = n4; i5 = n5; i6 = n6; i7 = n7;
        e = en; have = haven;
    }
    for (; e < e1; e++) {                              // tail (< 8 edges)
        uint4 v = *(const uint4*)(base + (size_t)ssrc[e] * DD);
        acc8(acc, v);
    }
    uint4 o;
    o.x = pack2(acc[0], acc[1]); o.y = pack2(acc[2], acc[3]);
    o.z = pack2(acc[4], acc[5]); o.w = pack2(acc[6], acc[7]);
    *(uint4*)(Z + (size_t)node * DD + foff) = o;
}

// ---------- MLP: out = relu(relu(z@W1+b1)@W2+b2) ----------
// block 256 = 4 waves; wave owns 16 rows; wave-private (no barriers).
__global__ __launch_bounds__(256) void mlp_kernel(
    const u16* __restrict__ Zin, const u16* __restrict__ Wt1, const float* __restrict__ b1,
    const u16* __restrict__ Wt2, const float* __restrict__ b2,
    u16* __restrict__ Hout) {
    __shared__ u16 zb[64][136];   // row stride 272B: 16B-aligned, wave-private 16-row tiles
    const int wave = threadIdx.x >> 6;
    const int lane = threadIdx.x & 63;
    const int m16 = lane & 15;
    const int quad = lane >> 4;
    const int row0 = blockIdx.x * 64 + wave * 16;

    // stage 16 rows x 256B, fully coalesced (1KB per instruction)
#pragma unroll
    for (int p = 0; p < 4; p++) {
        int idx = p * 64 + lane;          // 0..255 16B-chunks
        int r = idx >> 4, ch = idx & 15;
        if (row0 + r < NN)
            *(uint4*)&zb[wave * 16 + r][ch * 8] = *(const uint4*)(Zin + (size_t)(row0 + r) * DD + ch * 8);
    }

    // ---- GEMM1
    bf16x8 afr[4];
#pragma unroll
    for (int kk = 0; kk < 4; kk++)
        afr[kk] = *(const bf16x8*)&zb[wave * 16 + m16][kk * 32 + quad * 8];
    f32x4 acc[8];
#pragma unroll
    for (int nt = 0; nt < 8; nt++) acc[nt] = (f32x4){0.f, 0.f, 0.f, 0.f};
#pragma unroll
    for (int kk = 0; kk < 4; kk++) {
#pragma unroll
        for (int nt = 0; nt < 8; nt++) {
            bf16x8 bfr = *(const bf16x8*)(Wt1 + ((nt * 16 + m16) << 7) + kk * 32 + quad * 8);
            acc[nt] = __builtin_amdgcn_mfma_f32_16x16x32_bf16(afr[kk], bfr, acc[nt], 0, 0, 0);
        }
    }
#pragma unroll
    for (int nt = 0; nt < 8; nt++) {      // y -> zb (zb dead after afr read; wave-private)
        int col = nt * 16 + m16;
        float bias = b1[col];
#pragma unroll
        for (int r = 0; r < 4; r++) {
            float yv = acc[nt][r] + bias;
            yv = yv > 0.f ? yv : 0.f;
            zb[wave * 16 + quad * 4 + r][col] = f2bf(yv);
        }
    }

    // ---- GEMM2
#pragma unroll
    for (int kk = 0; kk < 4; kk++)
        afr[kk] = *(const bf16x8*)&zb[wave * 16 + m16][kk * 32 + quad * 8];
#pragma unroll
    for (int nt = 0; nt < 8; nt++) acc[nt] = (f32x4){0.f, 0.f, 0.f, 0.f};
#pragma unroll
    for (int kk = 0; kk < 4; kk++) {
#pragma unroll
        for (int nt = 0; nt < 8; nt++) {
            bf16x8 bfr = *(const bf16x8*)(Wt2 + ((nt * 16 + m16) << 7) + kk * 32 + quad * 8);
            acc[nt] = __builtin_amdgcn_mfma_f32_16x16x32_bf16(afr[kk], bfr, acc[nt], 0, 0, 0);
        }
    }
#pragma unroll
    for (int nt = 0; nt < 8; nt++) {      // stage output in zb, then coalesced store
        int col = nt * 16 + m16;
        float bias = b2[col];
#pragma unroll
        for (int r = 0; r < 4; r++) {
            float ov = acc[nt][r] + bias;
            ov = ov > 0.f ? ov : 0.f;
            zb[wave * 16 + quad * 4 + r][col] = f2bf(ov);
        }
    }
#pragma unroll
    for (int p = 0; p < 4; p++) {
        int idx = p * 64 + lane;
        int r = idx >> 4, ch = idx & 15;
        if (row0 + r < NN)
            *(uint4*)(Hout + (size_t)(row0 + r) * DD + ch * 8) = *(const uint4*)&zb[wave * 16 + r][ch * 8];
    }
}

// ---------- mean-pool partial sums ----------
__global__ void pool_kernel(const u16* __restrict__ H2, const int* __restrict__ gstart,
                            float* __restrict__ pool) {
    int g = blockIdx.x >> 5, q = blockIdx.x & 31;
    int f = threadIdx.x;   // 0..127
    int s = gstart[g], e = gstart[g + 1];
    float sum = 0.f;
    for (int n = s + q; n < e; n += 32) sum += bf2f(H2[(size_t)n * DD + f]);
    atomicAdd(&pool[g * DD + f], sum);
}

// ---------- classifier (fp32) ----------
__global__ void cls_kernel(const float* __restrict__ pool, const int* __restrict__ gstart,
                           const float* __restrict__ Wc1, const float* __restrict__ bc1,
                           const float* __restrict__ Wc2, const float* __restrict__ bc2,
                           float* __restrict__ out) {
    __shared__ float hg[128];
    __shared__ float y1[128];
    int g = blockIdx.x;
    int t = threadIdx.x;   // 128 threads
    int cnt = gstart[g + 1] - gstart[g];
    float inv = 1.f / (float)(cnt > 1 ? cnt : 1);
    hg[t] = pool[g * DD + t] * inv;
    __syncthreads();
    float a = bc1[t];
    for (int k = 0; k < DD; k++) a += hg[k] * Wc1[k * DD + t];
    y1[t] = a > 0.f ? a : 0.f;
    __syncthreads();
    if (t < CC) {
        float o = bc2[t];
        for (int k = 0; k < DD; k++) o += y1[k] * Wc2[k * CC + t];
        out[g * CC + t] = o;
    }
}

extern "C" void kernel_launch(void* const* d_in, const int* in_sizes, int n_in,
                              void* d_out, int out_size, void* d_ws, size_t ws_size,
                              hipStream_t stream) {
    const float* h    = (const float*)d_in[0];
    const int*   src  = (const int*)d_in[1];
    const int*   dst  = (const int*)d_in[2];
    const int*   gids = (const int*)d_in[3];
    const float* W1a  = (const float*)d_in[4];
    const float* b1a  = (const float*)d_in[5];
    const float* W2a  = (const float*)d_in[6];
    const float* b2a  = (const float*)d_in[7];
    const float* W1b  = (const float*)d_in[8];
    const float* b1b  = (const float*)d_in[9];
    const float* W2b  = (const float*)d_in[10];
    const float* b2b  = (const float*)d_in[11];
    const float* Wc1  = (const float*)d_in[12];
    const float* bc1  = (const float*)d_in[13];
    const float* Wc2  = (const float*)d_in[14];
    const float* bc2  = (const float*)d_in[15];
    float* out = (float*)d_out;

    char* ws = (char*)d_ws;
    u16*   H0     = (u16*)(ws);                    // 12,800,000 B
    u16*   H1     = (u16*)(ws + 12800000);         // 12,800,000 B
    u16*   H2     = (u16*)(ws + 25600000);         // 12,800,000 B
    u16*   Wt     = (u16*)(ws + 38400000);         // 131,072 B
    int*   deg    = (int*)(ws + 38531072);         // 200,000 B (zero range start)
    int*   cur    = (int*)(ws + 38731072);         // 200,000 B (contiguous with deg)
    float* pool   = (float*)(ws + 38931072);       // 8,192 B (contiguous with cur)
    int*   offs   = (int*)(ws + 38939264);         // 200,004 B
    int*   ssrc   = (int*)(ws + 39139268);         // 3,200,000 B
    int*   gstart = (int*)(ws + 42339268);         // 68 B
    int*   bsum   = (int*)(ws + 25600000);         // aliases H2 (dead until agg1 writes)
    u16*   Z1     = H2;                            // scratch z, layer 1 (H2 written later by mlp2)
    u16*   Z2     = H0;                            // scratch z, layer 2 (H0 dead after agg1)

    prep_kernel<<<dim3((PTOT + 255) / 256), dim3(256), 0, stream>>>(h, W1a, W2a, W1b, W2b, deg, H0, Wt);
    hist_kernel<<<dim3((EE + 255) / 256), dim3(256), 0, stream>>>(dst, deg);
    scanA_kernel<<<dim3(NB), dim3(256), 0, stream>>>(deg, offs, bsum);
    scanB_kernel<<<dim3(1), dim3(256), 0, stream>>>(bsum, offs, gids, gstart);
    scanC_kernel<<<dim3(NB), dim3(256), 0, stream>>>(offs, bsum);
    scatter_kernel<<<dim3((EE + 255) / 256), dim3(256), 0, stream>>>(src, dst, offs, cur, ssrc);
    agg_kernel<<<dim3((2 * NN + 31) / 32), dim3(256), 0, stream>>>(H0, offs, ssrc, Z1);
    mlp_kernel<<<dim3((NN + 63) / 64), dim3(256), 0, stream>>>(Z1, Wt, b1a, Wt + 16384, b2a, H1);
    agg_kernel<<<dim3((2 * NN + 31) / 32), dim3(256), 0, stream>>>(H1, offs, ssrc, Z2);
    mlp_kernel<<<dim3((NN + 63) / 64), dim3(256), 0, stream>>>(Z2, Wt + 32768, b1b, Wt + 49152, b2b, H2);
    pool_kernel<<<dim3(GG * 32), dim3(128), 0, stream>>>(H2, gstart, pool);
    cls_kernel<<<dim3(GG), dim3(128), 0, stream>>>(pool, gstart, Wc1, bc1, Wc2, bc2, out);
}

// Round 6
// 320.662 us; speedup vs baseline: 1.1385x; 1.1385x over previous
//
#include <hip/hip_runtime.h>
#include <stdint.h>

#define NN 50000
#define EE 800000
#define DD 128
#define GG 16
#define CC 10
#define NBK 196                   // coarse buckets of 256 nodes: 196*256 = 50176 >= NN
#define BCH 4096                  // edges per sort block: 196*4096 = 802816 >= EE
#define SMAX 5120                 // max edges per bucket (mean 4096, +16 sigma margin)

typedef unsigned short u16;
typedef __bf16 bf16x8 __attribute__((ext_vector_type(8)));
typedef float f32x4 __attribute__((ext_vector_type(4)));

__device__ inline u16 f2bf(float f) {
    unsigned u = __float_as_uint(f);
    u = u + 0x7fffu + ((u >> 16) & 1u);   // RNE
    return (u16)(u >> 16);
}
__device__ inline unsigned pack2(float a, float b) {
    return (unsigned)f2bf(a) | ((unsigned)f2bf(b) << 16);
}
__device__ inline float bf2f(unsigned bits16) { return __uint_as_float(bits16 << 16); }
__device__ inline void acc8(float* a, uint4 v) {
    a[0] += __uint_as_float(v.x << 16); a[1] += __uint_as_float(v.x & 0xffff0000u);
    a[2] += __uint_as_float(v.y << 16); a[3] += __uint_as_float(v.y & 0xffff0000u);
    a[4] += __uint_as_float(v.z << 16); a[5] += __uint_as_float(v.z & 0xffff0000u);
    a[6] += __uint_as_float(v.w << 16); a[7] += __uint_as_float(v.w & 0xffff0000u);
}

// ---------- fused prep: zero pool, cvt h->bf16, transpose+cast weights ----------
#define PZ (GG * DD)                   // 2048 floats (pool) to zero
#define PC (NN * DD / 4)               // 1600000 float4 groups
#define PW (4 * DD * DD)               // 65536 weight elements
#define PTOT (PZ + PC + PW)

__global__ void prep_kernel(const float* __restrict__ h,
                            const float* __restrict__ a, const float* __restrict__ b,
                            const float* __restrict__ c, const float* __restrict__ d,
                            int* __restrict__ zbase, u16* __restrict__ H0,
                            u16* __restrict__ wt) {
    int i = blockIdx.x * 256 + threadIdx.x;
    if (i < PZ) { zbase[i] = 0; return; }
    i -= PZ;
    if (i < PC) {
        int j = i * 4;
        float4 v = *(const float4*)(h + j);
        ushort4 o;
        o.x = f2bf(v.x); o.y = f2bf(v.y); o.z = f2bf(v.z); o.w = f2bf(v.w);
        *(ushort4*)(H0 + j) = o;
        return;
    }
    i -= PC;
    if (i < PW) {
        int m = i >> 14, r = i & 16383, k = r >> 7, j = r & 127;
        const float* W = (m == 0) ? a : (m == 1) ? b : (m == 2) ? c : d;
        wt[(m << 14) + (j << 7) + k] = f2bf(W[(k << 7) + j]);
    }
}

// ---------- 2-level counting sort of edges by dst (replaces hist/scan/scatter) ----------
// Pass 1: per-block LDS histogram over 196 coarse buckets (256 nodes each).
__global__ __launch_bounds__(256) void sortP1_kernel(const int* __restrict__ dst,
                                                     int* __restrict__ counts) {
    __shared__ int hist[NBK];
    int b = blockIdx.x, t = threadIdx.x;
    for (int i = t; i < NBK; i += 256) hist[i] = 0;
    __syncthreads();
    int e0 = b * BCH, e1 = min(e0 + BCH, EE);
    for (int e = e0 + t; e < e1; e += 256) atomicAdd(&hist[dst[e] >> 8], 1);
    __syncthreads();
    for (int i = t; i < NBK; i += 256) counts[b * NBK + i] = hist[i];
}

// Pass 2 (1 block): counts[b][j] -> global write base (in place); bucket bases; gstart.
__global__ __launch_bounds__(256) void sortP2_kernel(int* __restrict__ counts,
                                                     int* __restrict__ bbase,
                                                     const int* __restrict__ gids,
                                                     int* __restrict__ gstart) {
    __shared__ int tmp[256];
    int t = threadIdx.x;
    if (t <= GG) {                                  // graph boundary binary search
        int lo = 0, hi = NN;
        while (lo < hi) { int mid = (lo + hi) >> 1; if (gids[mid] < t) lo = mid + 1; else hi = mid; }
        gstart[t] = lo;
    }
    int s = 0;
    if (t < NBK) {
        for (int b = 0; b < NBK; b++) {             // column prefix (in place)
            int c = counts[b * NBK + t];
            counts[b * NBK + t] = s;
            s += c;
        }
    }
    tmp[t] = (t < NBK) ? s : 0;
    __syncthreads();
    for (int off = 1; off < 256; off <<= 1) {       // inclusive scan of column sums
        int x = (t >= off) ? tmp[t - off] : 0;
        __syncthreads();
        tmp[t] += x;
        __syncthreads();
    }
    int base = tmp[t] - ((t < NBK) ? s : 0);        // exclusive bucket base
    if (t < NBK) {
        bbase[t] = base;
        for (int b = 0; b < NBK; b++) counts[b * NBK + t] += base;
    }
    if (t == NBK - 1) bbase[NBK] = tmp[t];          // = EE
}

// Pass 3: scatter (src,dst) pairs into bucket-contiguous regions (8B runs per bucket).
__global__ __launch_bounds__(256) void sortP3_kernel(const int* __restrict__ src,
                                                     const int* __restrict__ dst,
                                                     const int* __restrict__ counts,
                                                     int2* __restrict__ epair) {
    __shared__ int curs[NBK];
    int b = blockIdx.x, t = threadIdx.x;
    for (int i = t; i < NBK; i += 256) curs[i] = counts[b * NBK + i];
    __syncthreads();
    int e0 = b * BCH, e1 = min(e0 + BCH, EE);
    for (int e = e0 + t; e < e1; e += 256) {
        int d = dst[e], s = src[e];
        int p = atomicAdd(&curs[d >> 8], 1);
        epair[p] = make_int2(s, d);
    }
}

// Pass 4 (1 block per bucket): local counting sort over 256 nodes; writes offs + ssrc coalesced.
__global__ __launch_bounds__(256) void sortP4_kernel(const int2* __restrict__ epair,
                                                     const int* __restrict__ bbase,
                                                     int* __restrict__ offs,
                                                     int* __restrict__ ssrc) {
    __shared__ int hist[256];
    __shared__ int curs[256];
    __shared__ int stage[SMAX];
    int j = blockIdx.x, t = threadIdx.x;
    int n0 = j << 8;
    int b0 = bbase[j], b1 = bbase[j + 1];
    hist[t] = 0;
    __syncthreads();
    for (int e = b0 + t; e < b1; e += 256) atomicAdd(&hist[epair[e].y - n0], 1);
    __syncthreads();
    int deg = hist[t];
    for (int off = 1; off < 256; off <<= 1) {       // inclusive scan
        int x = (t >= off) ? hist[t - off] : 0;
        __syncthreads();
        hist[t] += x;
        __syncthreads();
    }
    int loff = hist[t] - deg;                       // exclusive local offset
    curs[t] = loff;
    if (n0 + t <= NN) offs[n0 + t] = b0 + loff;     // block 195/t=80 writes offs[NN]=EE
    __syncthreads();
    for (int e = b0 + t; e < b1; e += 256) {
        int2 pr = epair[e];
        int p = atomicAdd(&curs[pr.y - n0], 1);
        stage[p] = pr.x;
    }
    __syncthreads();
    int n = b1 - b0;
    for (int i = t; i < n; i += 256) ssrc[b0 + i] = stage[i];   // coalesced
}

// ---------- aggregation: z = h + sum_{incoming} h_src ----------
// work item = (node, 128B half-row); 8 lanes per item, 8 items per wave.
// Edge loop: software-pipelined unroll-8 with next-batch index prefetch.
__global__ __launch_bounds__(256) void agg_kernel(
    const u16* __restrict__ Hin, const int* __restrict__ offs,
    const int* __restrict__ ssrc, u16* __restrict__ Z) {
    int gid = blockIdx.x * 32 + (threadIdx.x >> 3);   // 0..99999
    int lid = threadIdx.x & 7;
    if (gid >= 2 * NN) return;
    int node = gid >> 1;
    int foff = (gid & 1) * 64 + lid * 8;              // 16B slice
    const u16* base = Hin + foff;

    float acc[8] = {0.f, 0.f, 0.f, 0.f, 0.f, 0.f, 0.f, 0.f};
    uint4 vs = *(const uint4*)(base + (size_t)node * DD);
    int e = offs[node], e1 = offs[node + 1];
    acc8(acc, vs);                                    // self term (eps=0)

    int i0 = 0, i1 = 0, i2 = 0, i3 = 0, i4 = 0, i5 = 0, i6 = 0, i7 = 0;
    bool have = (e + 8 <= e1);
    if (have) {
        i0 = ssrc[e];     i1 = ssrc[e + 1]; i2 = ssrc[e + 2]; i3 = ssrc[e + 3];
        i4 = ssrc[e + 4]; i5 = ssrc[e + 5]; i6 = ssrc[e + 6]; i7 = ssrc[e + 7];
    }
    while (have) {
        int en = e + 8;
        bool haven = (en + 8 <= e1);
        int n0 = i0, n1 = i1, n2 = i2, n3 = i3, n4 = i4, n5 = i5, n6 = i6, n7 = i7;
        if (haven) {                                   // prefetch next batch indices
            n0 = ssrc[en];     n1 = ssrc[en + 1]; n2 = ssrc[en + 2]; n3 = ssrc[en + 3];
            n4 = ssrc[en + 4]; n5 = ssrc[en + 5]; n6 = ssrc[en + 6]; n7 = ssrc[en + 7];
        }
        uint4 v0 = *(const uint4*)(base + (size_t)i0 * DD);
        uint4 v1 = *(const uint4*)(base + (size_t)i1 * DD);
        uint4 v2 = *(const uint4*)(base + (size_t)i2 * DD);
        uint4 v3 = *(const uint4*)(base + (size_t)i3 * DD);
        uint4 v4 = *(const uint4*)(base + (size_t)i4 * DD);
        uint4 v5 = *(const uint4*)(base + (size_t)i5 * DD);
        uint4 v6 = *(const uint4*)(base + (size_t)i6 * DD);
        uint4 v7 = *(const uint4*)(base + (size_t)i7 * DD);
        acc8(acc, v0); acc8(acc, v1); acc8(acc, v2); acc8(acc, v3);
        acc8(acc, v4); acc8(acc, v5); acc8(acc, v6); acc8(acc, v7);
        i0 = n0; i1 = n1; i2 = n2; i3 = n3; i4 = n4; i5 = n5; i6 = n6; i7 = n7;
        e = en; have = haven;
    }
    for (; e < e1; e++) {                              // tail (< 8 edges)
        uint4 v = *(const uint4*)(base + (size_t)ssrc[e] * DD);
        acc8(acc, v);
    }
    uint4 o;
    o.x = pack2(acc[0], acc[1]); o.y = pack2(acc[2], acc[3]);
    o.z = pack2(acc[4], acc[5]); o.w = pack2(acc[6], acc[7]);
    *(uint4*)(Z + (size_t)node * DD + foff) = o;
}

// ---------- MLP: out = relu(relu(z@W1+b1)@W2+b2) ----------
// block 256 = 4 waves; wave owns 16 rows; wave-private (no barriers).
__global__ __launch_bounds__(256) void mlp_kernel(
    const u16* __restrict__ Zin, const u16* __restrict__ Wt1, const float* __restrict__ b1,
    const u16* __restrict__ Wt2, const float* __restrict__ b2,
    u16* __restrict__ Hout) {
    __shared__ u16 zb[64][136];   // row stride 272B: 16B-aligned, wave-private 16-row tiles
    const int wave = threadIdx.x >> 6;
    const int lane = threadIdx.x & 63;
    const int m16 = lane & 15;
    const int quad = lane >> 4;
    const int row0 = blockIdx.x * 64 + wave * 16;

    // stage 16 rows x 256B, fully coalesced (1KB per instruction)
#pragma unroll
    for (int p = 0; p < 4; p++) {
        int idx = p * 64 + lane;          // 0..255 16B-chunks
        int r = idx >> 4, ch = idx & 15;
        if (row0 + r < NN)
            *(uint4*)&zb[wave * 16 + r][ch * 8] = *(const uint4*)(Zin + (size_t)(row0 + r) * DD + ch * 8);
    }

    // ---- GEMM1
    bf16x8 afr[4];
#pragma unroll
    for (int kk = 0; kk < 4; kk++)
        afr[kk] = *(const bf16x8*)&zb[wave * 16 + m16][kk * 32 + quad * 8];
    f32x4 acc[8];
#pragma unroll
    for (int nt = 0; nt < 8; nt++) acc[nt] = (f32x4){0.f, 0.f, 0.f, 0.f};
#pragma unroll
    for (int kk = 0; kk < 4; kk++) {
#pragma unroll
        for (int nt = 0; nt < 8; nt++) {
            bf16x8 bfr = *(const bf16x8*)(Wt1 + ((nt * 16 + m16) << 7) + kk * 32 + quad * 8);
            acc[nt] = __builtin_amdgcn_mfma_f32_16x16x32_bf16(afr[kk], bfr, acc[nt], 0, 0, 0);
        }
    }
#pragma unroll
    for (int nt = 0; nt < 8; nt++) {      // y -> zb (zb dead after afr read; wave-private)
        int col = nt * 16 + m16;
        float bias = b1[col];
#pragma unroll
        for (int r = 0; r < 4; r++) {
            float yv = acc[nt][r] + bias;
            yv = yv > 0.f ? yv : 0.f;
            zb[wave * 16 + quad * 4 + r][col] = f2bf(yv);
        }
    }

    // ---- GEMM2
#pragma unroll
    for (int kk = 0; kk < 4; kk++)
        afr[kk] = *(const bf16x8*)&zb[wave * 16 + m16][kk * 32 + quad * 8];
#pragma unroll
    for (int nt = 0; nt < 8; nt++) acc[nt] = (f32x4){0.f, 0.f, 0.f, 0.f};
#pragma unroll
    for (int kk = 0; kk < 4; kk++) {
#pragma unroll
        for (int nt = 0; nt < 8; nt++) {
            bf16x8 bfr = *(const bf16x8*)(Wt2 + ((nt * 16 + m16) << 7) + kk * 32 + quad * 8);
            acc[nt] = __builtin_amdgcn_mfma_f32_16x16x32_bf16(afr[kk], bfr, acc[nt], 0, 0, 0);
        }
    }
#pragma unroll
    for (int nt = 0; nt < 8; nt++) {      // stage output in zb, then coalesced store
        int col = nt * 16 + m16;
        float bias = b2[col];
#pragma unroll
        for (int r = 0; r < 4; r++) {
            float ov = acc[nt][r] + bias;
            ov = ov > 0.f ? ov : 0.f;
            zb[wave * 16 + quad * 4 + r][col] = f2bf(ov);
        }
    }
#pragma unroll
    for (int p = 0; p < 4; p++) {
        int idx = p * 64 + lane;
        int r = idx >> 4, ch = idx & 15;
        if (row0 + r < NN)
            *(uint4*)(Hout + (size_t)(row0 + r) * DD + ch * 8) = *(const uint4*)&zb[wave * 16 + r][ch * 8];
    }
}

// ---------- mean-pool partial sums ----------
__global__ void pool_kernel(const u16* __restrict__ H2, const int* __restrict__ gstart,
                            float* __restrict__ pool) {
    int g = blockIdx.x >> 5, q = blockIdx.x & 31;
    int f = threadIdx.x;   // 0..127
    int s = gstart[g], e = gstart[g + 1];
    float sum = 0.f;
    for (int n = s + q; n < e; n += 32) sum += bf2f(H2[(size_t)n * DD + f]);
    atomicAdd(&pool[g * DD + f], sum);
}

// ---------- classifier (fp32) ----------
__global__ void cls_kernel(const float* __restrict__ pool, const int* __restrict__ gstart,
                           const float* __restrict__ Wc1, const float* __restrict__ bc1,
                           const float* __restrict__ Wc2, const float* __restrict__ bc2,
                           float* __restrict__ out) {
    __shared__ float hg[128];
    __shared__ float y1[128];
    int g = blockIdx.x;
    int t = threadIdx.x;   // 128 threads
    int cnt = gstart[g + 1] - gstart[g];
    float inv = 1.f / (float)(cnt > 1 ? cnt : 1);
    hg[t] = pool[g * DD + t] * inv;
    __syncthreads();
    float a = bc1[t];
    for (int k = 0; k < DD; k++) a += hg[k] * Wc1[k * DD + t];
    y1[t] = a > 0.f ? a : 0.f;
    __syncthreads();
    if (t < CC) {
        float o = bc2[t];
        for (int k = 0; k < DD; k++) o += y1[k] * Wc2[k * CC + t];
        out[g * CC + t] = o;
    }
}

extern "C" void kernel_launch(void* const* d_in, const int* in_sizes, int n_in,
                              void* d_out, int out_size, void* d_ws, size_t ws_size,
                              hipStream_t stream) {
    const float* h    = (const float*)d_in[0];
    const int*   src  = (const int*)d_in[1];
    const int*   dst  = (const int*)d_in[2];
    const int*   gids = (const int*)d_in[3];
    const float* W1a  = (const float*)d_in[4];
    const float* b1a  = (const float*)d_in[5];
    const float* W2a  = (const float*)d_in[6];
    const float* b2a  = (const float*)d_in[7];
    const float* W1b  = (const float*)d_in[8];
    const float* b1b  = (const float*)d_in[9];
    const float* W2b  = (const float*)d_in[10];
    const float* b2b  = (const float*)d_in[11];
    const float* Wc1  = (const float*)d_in[12];
    const float* bc1  = (const float*)d_in[13];
    const float* Wc2  = (const float*)d_in[14];
    const float* bc2  = (const float*)d_in[15];
    float* out = (float*)d_out;

    char* ws = (char*)d_ws;
    u16*   H0     = (u16*)(ws);                    // 12,800,000 B
    u16*   H1     = (u16*)(ws + 12800000);         // 12,800,000 B
    u16*   H2     = (u16*)(ws + 25600000);         // 12,800,000 B
    u16*   Wt     = (u16*)(ws + 38400000);         // 131,072 B
    float* pool   = (float*)(ws + 38531072);       // 8,192 B (zeroed by prep)
    int*   offs   = (int*)(ws + 38539264);         // 200,004 B
    int*   ssrc   = (int*)(ws + 38739268);         // 3,200,000 B
    int*   gstart = (int*)(ws + 41939268);         // 68 B
    int*   counts = (int*)(ws + 41939336);         // 153,664 B (196x196)
    int*   bbase  = (int*)(ws + 42093000);         // 788 B
    int2*  epair  = (int2*)(ws + 42093792);        // 6,400,000 B (8B aligned)
    u16*   Z1     = H2;                            // scratch z, layer 1 (H2 written later by mlp2)
    u16*   Z2     = H0;                            // scratch z, layer 2 (H0 dead after agg1)

    prep_kernel<<<dim3((PTOT + 255) / 256), dim3(256), 0, stream>>>(h, W1a, W2a, W1b, W2b, (int*)pool, H0, Wt);
    sortP1_kernel<<<dim3(NBK), dim3(256), 0, stream>>>(dst, counts);
    sortP2_kernel<<<dim3(1), dim3(256), 0, stream>>>(counts, bbase, gids, gstart);
    sortP3_kernel<<<dim3(NBK), dim3(256), 0, stream>>>(src, dst, counts, epair);
    sortP4_kernel<<<dim3(NBK), dim3(256), 0, stream>>>(epair, bbase, offs, ssrc);
    agg_kernel<<<dim3((2 * NN + 31) / 32), dim3(256), 0, stream>>>(H0, offs, ssrc, Z1);
    mlp_kernel<<<dim3((NN + 63) / 64), dim3(256), 0, stream>>>(Z1, Wt, b1a, Wt + 16384, b2a, H1);
    agg_kernel<<<dim3((2 * NN + 31) / 32), dim3(256), 0, stream>>>(H1, offs, ssrc, Z2);
    mlp_kernel<<<dim3((NN + 63) / 64), dim3(256), 0, stream>>>(Z2, Wt + 32768, b1b, Wt + 49152, b2b, H2);
    pool_kernel<<<dim3(GG * 32), dim3(128), 0, stream>>>(H2, gstart, pool);
    cls_kernel<<<dim3(GG), dim3(128), 0, stream>>>(pool, gstart, Wc1, bc1, Wc2, bc2, out);
}

// Round 7
// 305.557 us; speedup vs baseline: 1.1947x; 1.0494x over previous
//
#include <hip/hip_runtime.h>
#include <stdint.h>

#define NN 50000
#define EE 800000
#define DD 128
#define GG 16
#define CC 10
#define NBK 196                   // coarse buckets of 256 nodes: 196*256 = 50176 >= NN
#define BCH 4096                  // edges per sort block: 196*4096 = 802816 >= EE
#define SMAX 5120                 // max edges per bucket (mean 4096, wide margin)

typedef unsigned short u16;
typedef __bf16 bf16x8 __attribute__((ext_vector_type(8)));
typedef float f32x4 __attribute__((ext_vector_type(4)));

__device__ inline u16 f2bf(float f) {
    unsigned u = __float_as_uint(f);
    u = u + 0x7fffu + ((u >> 16) & 1u);   // RNE
    return (u16)(u >> 16);
}
__device__ inline unsigned pack2(float a, float b) {
    return (unsigned)f2bf(a) | ((unsigned)f2bf(b) << 16);
}
__device__ inline float bf2f(unsigned bits16) { return __uint_as_float(bits16 << 16); }
__device__ inline void acc8(float* a, uint4 v) {
    a[0] += __uint_as_float(v.x << 16); a[1] += __uint_as_float(v.x & 0xffff0000u);
    a[2] += __uint_as_float(v.y << 16); a[3] += __uint_as_float(v.y & 0xffff0000u);
    a[4] += __uint_as_float(v.z << 16); a[5] += __uint_as_float(v.z & 0xffff0000u);
    a[6] += __uint_as_float(v.w << 16); a[7] += __uint_as_float(v.w & 0xffff0000u);
}
__device__ inline void mand(uint4& v, int p) {     // zero the lane's contribution if !p
    unsigned m = p ? 0xffffffffu : 0u;
    v.x &= m; v.y &= m; v.z &= m; v.w &= m;
}

// ---------- fused prep: zero pool, cvt h->bf16, transpose+cast weights ----------
#define PZ (GG * DD)                   // 2048 floats (pool) to zero
#define PC (NN * DD / 4)               // 1600000 float4 groups
#define PW (4 * DD * DD)               // 65536 weight elements
#define PTOT (PZ + PC + PW)

__global__ void prep_kernel(const float* __restrict__ h,
                            const float* __restrict__ a, const float* __restrict__ b,
                            const float* __restrict__ c, const float* __restrict__ d,
                            int* __restrict__ zbase, u16* __restrict__ H0,
                            u16* __restrict__ wt) {
    int i = blockIdx.x * 256 + threadIdx.x;
    if (i < PZ) { zbase[i] = 0; return; }
    i -= PZ;
    if (i < PC) {
        int j = i * 4;
        float4 v = *(const float4*)(h + j);
        ushort4 o;
        o.x = f2bf(v.x); o.y = f2bf(v.y); o.z = f2bf(v.z); o.w = f2bf(v.w);
        *(ushort4*)(H0 + j) = o;
        return;
    }
    i -= PC;
    if (i < PW) {
        int m = i >> 14, r = i & 16383, k = r >> 7, j = r & 127;
        const float* W = (m == 0) ? a : (m == 1) ? b : (m == 2) ? c : d;
        wt[(m << 14) + (j << 7) + k] = f2bf(W[(k << 7) + j]);
    }
}

// ---------- 2-level counting sort of edges by dst ----------
// Pass 1: per-block LDS histogram over 196 coarse buckets (256 nodes each).
__global__ __launch_bounds__(256) void sortP1_kernel(const int* __restrict__ dst,
                                                     int* __restrict__ counts) {
    __shared__ int hist[NBK];
    int b = blockIdx.x, t = threadIdx.x;
    for (int i = t; i < NBK; i += 256) hist[i] = 0;
    __syncthreads();
    int e0 = b * BCH, e1 = min(e0 + BCH, EE);
    for (int e = e0 + t; e < e1; e += 256) atomicAdd(&hist[dst[e] >> 8], 1);
    __syncthreads();
    for (int i = t; i < NBK; i += 256) counts[b * NBK + i] = hist[i];
}

// Pass 2 (1 block): counts[b][j] -> global write base (in place); bucket bases; gstart.
__global__ __launch_bounds__(256) void sortP2_kernel(int* __restrict__ counts,
                                                     int* __restrict__ bbase,
                                                     const int* __restrict__ gids,
                                                     int* __restrict__ gstart) {
    __shared__ int tmp[256];
    int t = threadIdx.x;
    if (t <= GG) {                                  // graph boundary binary search
        int lo = 0, hi = NN;
        while (lo < hi) { int mid = (lo + hi) >> 1; if (gids[mid] < t) lo = mid + 1; else hi = mid; }
        gstart[t] = lo;
    }
    int s = 0;
    if (t < NBK) {
        for (int b = 0; b < NBK; b++) {             // column prefix (in place)
            int c = counts[b * NBK + t];
            counts[b * NBK + t] = s;
            s += c;
        }
    }
    tmp[t] = (t < NBK) ? s : 0;
    __syncthreads();
    for (int off = 1; off < 256; off <<= 1) {       // inclusive scan of column sums
        int x = (t >= off) ? tmp[t - off] : 0;
        __syncthreads();
        tmp[t] += x;
        __syncthreads();
    }
    int base = tmp[t] - ((t < NBK) ? s : 0);        // exclusive bucket base
    if (t < NBK) {
        bbase[t] = base;
        for (int b = 0; b < NBK; b++) counts[b * NBK + t] += base;
    }
    if (t == NBK - 1) bbase[NBK] = tmp[t];          // = EE
}

// Pass 3: scatter packed (src<<8 | dst&255) into bucket-contiguous regions.
__global__ __launch_bounds__(256) void sortP3_kernel(const int* __restrict__ src,
                                                     const int* __restrict__ dst,
                                                     const int* __restrict__ counts,
                                                     int* __restrict__ epack) {
    __shared__ int curs[NBK];
    int b = blockIdx.x, t = threadIdx.x;
    for (int i = t; i < NBK; i += 256) curs[i] = counts[b * NBK + i];
    __syncthreads();
    int e0 = b * BCH, e1 = min(e0 + BCH, EE);
    for (int e = e0 + t; e < e1; e += 256) {
        int d = dst[e], s = src[e];
        int p = atomicAdd(&curs[d >> 8], 1);
        epack[p] = (s << 8) | (d & 255);            // src<2^16, local dst 8b -> 24b
    }
}

// Pass 4 (1 block per bucket): local counting sort over 256 nodes; offs + ssrc coalesced.
__global__ __launch_bounds__(256) void sortP4_kernel(const int* __restrict__ epack,
                                                     const int* __restrict__ bbase,
                                                     int* __restrict__ offs,
                                                     int* __restrict__ ssrc) {
    __shared__ int hist[256];
    __shared__ int curs[256];
    __shared__ int stage[SMAX];
    int j = blockIdx.x, t = threadIdx.x;
    int n0 = j << 8;
    int b0 = bbase[j], b1 = bbase[j + 1];
    hist[t] = 0;
    __syncthreads();
    for (int e = b0 + t; e < b1; e += 256) atomicAdd(&hist[epack[e] & 255], 1);
    __syncthreads();
    int deg = hist[t];
    for (int off = 1; off < 256; off <<= 1) {       // inclusive scan
        int x = (t >= off) ? hist[t - off] : 0;
        __syncthreads();
        hist[t] += x;
        __syncthreads();
    }
    int loff = hist[t] - deg;                       // exclusive local offset
    curs[t] = loff;
    if (n0 + t <= NN) offs[n0 + t] = b0 + loff;     // block 195/t=80 writes offs[NN]=EE
    __syncthreads();
    for (int e = b0 + t; e < b1; e += 256) {
        int pk = epack[e];
        int p = atomicAdd(&curs[pk & 255], 1);
        stage[p] = pk >> 8;                         // src
    }
    __syncthreads();
    int n = b1 - b0;
    for (int i = t; i < n; i += 256) ssrc[b0 + i] = stage[i];   // coalesced
}

// ---------- aggregation: z = h + sum_{incoming} h_src ----------
// work item = (node, 128B half-row); 8 lanes per item, 8 items per wave.
// Edge loop: ceil(deg/8) chunks of 8 predicated loads (index clamped, value
// AND-masked to 0) with next-chunk index prefetch -> NO serial tail; all loads
// stay in the 8-deep pipeline.
__global__ __launch_bounds__(256) void agg_kernel(
    const u16* __restrict__ Hin, const int* __restrict__ offs,
    const int* __restrict__ ssrc, u16* __restrict__ Z) {
    int gid = blockIdx.x * 32 + (threadIdx.x >> 3);   // 0..99999
    int lid = threadIdx.x & 7;
    if (gid >= 2 * NN) return;
    int node = gid >> 1;
    int foff = (gid & 1) * 64 + lid * 8;              // 16B slice
    const u16* base = Hin + foff;

    float acc[8] = {0.f, 0.f, 0.f, 0.f, 0.f, 0.f, 0.f, 0.f};
    uint4 vs = *(const uint4*)(base + (size_t)node * DD);
    int e0 = offs[node], e1 = offs[node + 1];
    acc8(acc, vs);                                    // self term (eps=0)

    int nch = (e1 - e0 + 7) >> 3;
    if (nch > 0) {
        int elast = e1 - 1;
        int i0 = ssrc[e0];
        int i1 = ssrc[min(e0 + 1, elast)];
        int i2 = ssrc[min(e0 + 2, elast)];
        int i3 = ssrc[min(e0 + 3, elast)];
        int i4 = ssrc[min(e0 + 4, elast)];
        int i5 = ssrc[min(e0 + 5, elast)];
        int i6 = ssrc[min(e0 + 6, elast)];
        int i7 = ssrc[min(e0 + 7, elast)];
        int eb = e0;
        for (int c = 0; c < nch; c++) {
            int ebn = eb + 8;
            int n0 = i0, n1 = i1, n2 = i2, n3 = i3, n4 = i4, n5 = i5, n6 = i6, n7 = i7;
            if (c + 1 < nch) {                         // prefetch next chunk indices
                n0 = ssrc[ebn];
                n1 = ssrc[min(ebn + 1, elast)];
                n2 = ssrc[min(ebn + 2, elast)];
                n3 = ssrc[min(ebn + 3, elast)];
                n4 = ssrc[min(ebn + 4, elast)];
                n5 = ssrc[min(ebn + 5, elast)];
                n6 = ssrc[min(ebn + 6, elast)];
                n7 = ssrc[min(ebn + 7, elast)];
            }
            uint4 v0 = *(const uint4*)(base + (size_t)i0 * DD);
            uint4 v1 = *(const uint4*)(base + (size_t)i1 * DD);
            uint4 v2 = *(const uint4*)(base + (size_t)i2 * DD);
            uint4 v3 = *(const uint4*)(base + (size_t)i3 * DD);
            uint4 v4 = *(const uint4*)(base + (size_t)i4 * DD);
            uint4 v5 = *(const uint4*)(base + (size_t)i5 * DD);
            uint4 v6 = *(const uint4*)(base + (size_t)i6 * DD);
            uint4 v7 = *(const uint4*)(base + (size_t)i7 * DD);
            mand(v1, eb + 1 < e1); mand(v2, eb + 2 < e1); mand(v3, eb + 3 < e1);
            mand(v4, eb + 4 < e1); mand(v5, eb + 5 < e1); mand(v6, eb + 6 < e1);
            mand(v7, eb + 7 < e1);                     // slot 0 always valid
            acc8(acc, v0); acc8(acc, v1); acc8(acc, v2); acc8(acc, v3);
            acc8(acc, v4); acc8(acc, v5); acc8(acc, v6); acc8(acc, v7);
            i0 = n0; i1 = n1; i2 = n2; i3 = n3; i4 = n4; i5 = n5; i6 = n6; i7 = n7;
            eb = ebn;
        }
    }
    uint4 o;
    o.x = pack2(acc[0], acc[1]); o.y = pack2(acc[2], acc[3]);
    o.z = pack2(acc[4], acc[5]); o.w = pack2(acc[6], acc[7]);
    *(uint4*)(Z + (size_t)node * DD + foff) = o;
}

// ---------- MLP: out = relu(relu(z@W1+b1)@W2+b2) ----------
// block 256 = 4 waves; wave owns 16 rows; wave-private (no barriers).
__global__ __launch_bounds__(256) void mlp_kernel(
    const u16* __restrict__ Zin, const u16* __restrict__ Wt1, const float* __restrict__ b1,
    const u16* __restrict__ Wt2, const float* __restrict__ b2,
    u16* __restrict__ Hout) {
    __shared__ u16 zb[64][136];   // row stride 272B: 16B-aligned, wave-private 16-row tiles
    const int wave = threadIdx.x >> 6;
    const int lane = threadIdx.x & 63;
    const int m16 = lane & 15;
    const int quad = lane >> 4;
    const int row0 = blockIdx.x * 64 + wave * 16;

    // stage 16 rows x 256B, fully coalesced (1KB per instruction)
#pragma unroll
    for (int p = 0; p < 4; p++) {
        int idx = p * 64 + lane;          // 0..255 16B-chunks
        int r = idx >> 4, ch = idx & 15;
        if (row0 + r < NN)
            *(uint4*)&zb[wave * 16 + r][ch * 8] = *(const uint4*)(Zin + (size_t)(row0 + r) * DD + ch * 8);
    }

    // ---- GEMM1
    bf16x8 afr[4];
#pragma unroll
    for (int kk = 0; kk < 4; kk++)
        afr[kk] = *(const bf16x8*)&zb[wave * 16 + m16][kk * 32 + quad * 8];
    f32x4 acc[8];
#pragma unroll
    for (int nt = 0; nt < 8; nt++) acc[nt] = (f32x4){0.f, 0.f, 0.f, 0.f};
#pragma unroll
    for (int kk = 0; kk < 4; kk++) {
#pragma unroll
        for (int nt = 0; nt < 8; nt++) {
            bf16x8 bfr = *(const bf16x8*)(Wt1 + ((nt * 16 + m16) << 7) + kk * 32 + quad * 8);
            acc[nt] = __builtin_amdgcn_mfma_f32_16x16x32_bf16(afr[kk], bfr, acc[nt], 0, 0, 0);
        }
    }
#pragma unroll
    for (int nt = 0; nt < 8; nt++) {      // y -> zb (zb dead after afr read; wave-private)
        int col = nt * 16 + m16;
        float bias = b1[col];
#pragma unroll
        for (int r = 0; r < 4; r++) {
            float yv = acc[nt][r] + bias;
            yv = yv > 0.f ? yv : 0.f;
            zb[wave * 16 + quad * 4 + r][col] = f2bf(yv);
        }
    }

    // ---- GEMM2
#pragma unroll
    for (int kk = 0; kk < 4; kk++)
        afr[kk] = *(const bf16x8*)&zb[wave * 16 + m16][kk * 32 + quad * 8];
#pragma unroll
    for (int nt = 0; nt < 8; nt++) acc[nt] = (f32x4){0.f, 0.f, 0.f, 0.f};
#pragma unroll
    for (int kk = 0; kk < 4; kk++) {
#pragma unroll
        for (int nt = 0; nt < 8; nt++) {
            bf16x8 bfr = *(const bf16x8*)(Wt2 + ((nt * 16 + m16) << 7) + kk * 32 + quad * 8);
            acc[nt] = __builtin_amdgcn_mfma_f32_16x16x32_bf16(afr[kk], bfr, acc[nt], 0, 0, 0);
        }
    }
#pragma unroll
    for (int nt = 0; nt < 8; nt++) {      // stage output in zb, then coalesced store
        int col = nt * 16 + m16;
        float bias = b2[col];
#pragma unroll
        for (int r = 0; r < 4; r++) {
            float ov = acc[nt][r] + bias;
            ov = ov > 0.f ? ov : 0.f;
            zb[wave * 16 + quad * 4 + r][col] = f2bf(ov);
        }
    }
#pragma unroll
    for (int p = 0; p < 4; p++) {
        int idx = p * 64 + lane;
        int r = idx >> 4, ch = idx & 15;
        if (row0 + r < NN)
            *(uint4*)(Hout + (size_t)(row0 + r) * DD + ch * 8) = *(const uint4*)&zb[wave * 16 + r][ch * 8];
    }
}

// ---------- mean-pool partial sums ----------
__global__ void pool_kernel(const u16* __restrict__ H2, const int* __restrict__ gstart,
                            float* __restrict__ pool) {
    int g = blockIdx.x >> 5, q = blockIdx.x & 31;
    int f = threadIdx.x;   // 0..127
    int s = gstart[g], e = gstart[g + 1];
    float sum = 0.f;
    for (int n = s + q; n < e; n += 32) sum += bf2f(H2[(size_t)n * DD + f]);
    atomicAdd(&pool[g * DD + f], sum);
}

// ---------- classifier (fp32) ----------
__global__ void cls_kernel(const float* __restrict__ pool, const int* __restrict__ gstart,
                           const float* __restrict__ Wc1, const float* __restrict__ bc1,
                           const float* __restrict__ Wc2, const float* __restrict__ bc2,
                           float* __restrict__ out) {
    __shared__ float hg[128];
    __shared__ float y1[128];
    int g = blockIdx.x;
    int t = threadIdx.x;   // 128 threads
    int cnt = gstart[g + 1] - gstart[g];
    float inv = 1.f / (float)(cnt > 1 ? cnt : 1);
    hg[t] = pool[g * DD + t] * inv;
    __syncthreads();
    float a = bc1[t];
    for (int k = 0; k < DD; k++) a += hg[k] * Wc1[k * DD + t];
    y1[t] = a > 0.f ? a : 0.f;
    __syncthreads();
    if (t < CC) {
        float o = bc2[t];
        for (int k = 0; k < DD; k++) o += y1[k] * Wc2[k * CC + t];
        out[g * CC + t] = o;
    }
}

extern "C" void kernel_launch(void* const* d_in, const int* in_sizes, int n_in,
                              void* d_out, int out_size, void* d_ws, size_t ws_size,
                              hipStream_t stream) {
    const float* h    = (const float*)d_in[0];
    const int*   src  = (const int*)d_in[1];
    const int*   dst  = (const int*)d_in[2];
    const int*   gids = (const int*)d_in[3];
    const float* W1a  = (const float*)d_in[4];
    const float* b1a  = (const float*)d_in[5];
    const float* W2a  = (const float*)d_in[6];
    const float* b2a  = (const float*)d_in[7];
    const float* W1b  = (const float*)d_in[8];
    const float* b1b  = (const float*)d_in[9];
    const float* W2b  = (const float*)d_in[10];
    const float* b2b  = (const float*)d_in[11];
    const float* Wc1  = (const float*)d_in[12];
    const float* bc1  = (const float*)d_in[13];
    const float* Wc2  = (const float*)d_in[14];
    const float* bc2  = (const float*)d_in[15];
    float* out = (float*)d_out;

    char* ws = (char*)d_ws;
    u16*   H0     = (u16*)(ws);                    // 12,800,000 B
    u16*   H1     = (u16*)(ws + 12800000);         // 12,800,000 B
    u16*   H2     = (u16*)(ws + 25600000);         // 12,800,000 B
    u16*   Wt     = (u16*)(ws + 38400000);         // 131,072 B
    float* pool   = (float*)(ws + 38531072);       // 8,192 B (zeroed by prep)
    int*   offs   = (int*)(ws + 38539264);         // 200,004 B
    int*   ssrc   = (int*)(ws + 38739268);         // 3,200,000 B
    int*   gstart = (int*)(ws + 41939268);         // 68 B
    int*   counts = (int*)(ws + 41939336);         // 153,664 B (196x196)
    int*   bbase  = (int*)(ws + 42093000);         // 788 B
    int*   epack  = (int*)(ws + 42093792);         // 3,200,000 B (packed src|dstlocal)
    u16*   Z1     = H2;                            // scratch z, layer 1 (H2 written later by mlp2)
    u16*   Z2     = H0;                            // scratch z, layer 2 (H0 dead after agg1)

    prep_kernel<<<dim3((PTOT + 255) / 256), dim3(256), 0, stream>>>(h, W1a, W2a, W1b, W2b, (int*)pool, H0, Wt);
    sortP1_kernel<<<dim3(NBK), dim3(256), 0, stream>>>(dst, counts);
    sortP2_kernel<<<dim3(1), dim3(256), 0, stream>>>(counts, bbase, gids, gstart);
    sortP3_kernel<<<dim3(NBK), dim3(256), 0, stream>>>(src, dst, counts, epack);
    sortP4_kernel<<<dim3(NBK), dim3(256), 0, stream>>>(epack, bbase, offs, ssrc);
    agg_kernel<<<dim3((2 * NN + 31) / 32), dim3(256), 0, stream>>>(H0, offs, ssrc, Z1);
    mlp_kernel<<<dim3((NN + 63) / 64), dim3(256), 0, stream>>>(Z1, Wt, b1a, Wt + 16384, b2a, H1);
    agg_kernel<<<dim3((2 * NN + 31) / 32), dim3(256), 0, stream>>>(H1, offs, ssrc, Z2);
    mlp_kernel<<<dim3((NN + 63) / 64), dim3(256), 0, stream>>>(Z2, Wt + 32768, b1b, Wt + 49152, b2b, H2);
    pool_kernel<<<dim3(GG * 32), dim3(128), 0, stream>>>(H2, gstart, pool);
    cls_kernel<<<dim3(GG), dim3(128), 0, stream>>>(pool, gstart, Wc1, bc1, Wc2, bc2, out);
}